// Round 8
// baseline (1291.441 us; speedup 1.0000x reference)
//
#include <hip/hip_runtime.h>

#define NN 10000
#define NE 160000
#define DD 1280
#define MM 24

typedef __attribute__((ext_vector_type(8))) short bf16x8;
typedef __attribute__((ext_vector_type(4))) float f32x4;
typedef unsigned short u16;

// canonical bf16 weight-workspace offsets (elements)
#define O_nembW 0
#define O_nembB 1638400
#define O_msgW1 1639680
#define O_msgB1 2010880
#define O_msgW2 2011136
#define O_msgB2 2014592
#define O_cW1   2014848
#define O_cB1   2017792
#define O_cW2   2017920
#define O_nW1   2018048
#define O_nB1   2205824
#define O_nW2   2206080
#define O_nB2   2390400
#define O_lnG   2398080
#define O_lnB   2405760
#define TOTW    2413440

__device__ __forceinline__ float b2f(u16 u){
  union { unsigned int i; float f; } v; v.i = ((unsigned int)u) << 16; return v.f;
}
__device__ __forceinline__ u16 f2b(float f){
  union { float f; unsigned int i; } v; v.f = f;
  return (u16)((v.i + 0x7fffu + ((v.i >> 16) & 1u)) >> 16);
}
__device__ __forceinline__ float silu_f(float x){ return x / (1.f + __expf(-x)); }

__device__ __forceinline__ void gll16(const u16* g, u16* l){
  __builtin_amdgcn_global_load_lds(
      (const __attribute__((address_space(1))) void*)g,
      (__attribute__((address_space(3))) void*)l, 16, 0, 0);
}

// ---------------- dtype sniffer ----------------
__global__ __launch_bounds__(256) void k_sniff(const u16* __restrict__ h0, int* __restrict__ modep)
{
  __shared__ int cnt;
  if (threadIdx.x == 0) cnt = 0;
  __syncthreads();
  int local = 0;
  for (int i = threadIdx.x; i < 16384; i += 256){
    unsigned int e = (h0[i] >> 7) & 0xFF;
    if (e >= 0xE0) local++;
  }
  atomicAdd(&cnt, local);
  __syncthreads();
  if (threadIdx.x == 0) *modep = (cnt > 16) ? 0 : 1;   // 0=fp32 inputs, 1=bf16 inputs
}

// ---------------- convert all weights to canonical bf16 ----------------
__global__ __launch_bounds__(256) void k_cvtw(const int* __restrict__ modep,
    const void* p0, const void* p1, const void* p2, const void* p3, const void* p4,
    const void* p5, const void* p6, const void* p7, const void* p8, const void* p9,
    const void* p10, const void* p11, const void* p12, const void* p13, const void* p14,
    u16* __restrict__ wbf)
{
  int i = blockIdx.x * 256 + threadIdx.x;
  if (i >= TOTW) return;
  int mode = *modep;
  const void* src; int j; int sz;
  if      (i < O_nembB){ src = p0;  j = i - O_nembW; sz = 1638400; }
  else if (i < O_msgW1){ src = p1;  j = i - O_nembB; sz = 1280; }
  else if (i < O_msgB1){ src = p2;  j = i - O_msgW1; sz = 371088; }
  else if (i < O_msgW2){ src = p3;  j = i - O_msgB1; sz = 144; }
  else if (i < O_msgB2){ src = p4;  j = i - O_msgW2; sz = 3456; }
  else if (i < O_cW1)  { src = p5;  j = i - O_msgB2; sz = 144; }
  else if (i < O_cB1)  { src = p6;  j = i - O_cW1;   sz = 2880; }
  else if (i < O_cW2)  { src = p7;  j = i - O_cB1;   sz = 120; }
  else if (i < O_nW1)  { src = p8;  j = i - O_cW2;   sz = 120; }
  else if (i < O_nB1)  { src = p9;  j = i - O_nW1;   sz = 187776; }
  else if (i < O_nW2)  { src = p10; j = i - O_nB1;   sz = 144; }
  else if (i < O_nB2)  { src = p11; j = i - O_nW2;   sz = 184320; }
  else if (i < O_lnG)  { src = p12; j = i - O_nB2;   sz = 7680; }
  else if (i < O_lnB)  { src = p13; j = i - O_lnG;   sz = 7680; }
  else                 { src = p14; j = i - O_lnB;   sz = 7680; }
  u16 v = 0;
  if (j < sz) v = mode ? ((const u16*)src)[j] : f2b(((const float*)src)[j]);
  wbf[i] = v;
}

// ---------------- tiled transpose of node_emb_W: Wt[n][k] = W[k][n] ----------------
__global__ __launch_bounds__(256) void k_tr(const u16* __restrict__ win, u16* __restrict__ wout)
{
  __shared__ u16 tile[32][33];
  int bx = blockIdx.x % 40, by = blockIdx.x / 40;
  int tc = threadIdx.x & 31, tr = threadIdx.x >> 5;
  #pragma unroll
  for (int p = 0; p < 4; p++){
    int r = p*8 + tr;
    tile[r][tc] = win[(size_t)(by*32 + r)*1280 + bx*32 + tc];
  }
  __syncthreads();
  #pragma unroll
  for (int p = 0; p < 4; p++){
    int r = p*8 + tr;
    wout[(size_t)(bx*32 + r)*1280 + by*32 + tc] = tile[tc][r];
  }
}

// ---------------- pack per-layer proj weights transposed: wproj[l][n(80)][k(1280)] ----------
__global__ __launch_bounds__(256) void k_packproj(const u16* __restrict__ wbf, u16* __restrict__ wproj)
{
  int i = blockIdx.x * 256 + threadIdx.x;
  if (i >= 6*80*1280) return;
  int l = i / (80*1280);
  int rem = i - l*80*1280;
  int n = rem / 1280;
  int k = rem - n*1280;
  u16 v = 0;
  if (n < 24)       v = wbf[O_msgW1 + (size_t)l*2577*24 + (size_t)k*24 + n];
  else if (n < 48)  v = wbf[O_msgW1 + (size_t)l*2577*24 + (size_t)(1280+k)*24 + (n-24)];
  else if (n < 72)  v = wbf[O_nW1   + (size_t)l*1304*24 + (size_t)k*24 + (n-48)];
  wproj[i] = v;
}

// ---------------- pack nW2 transposed + K-padded: wn2p[l][n(1280)][k(32)] ----------------
__global__ __launch_bounds__(256) void k_packw2(const u16* __restrict__ wbf, u16* __restrict__ wn2p)
{
  int i = blockIdx.x * 256 + threadIdx.x;    // 6*1280*32 = 245760, grid exact
  int l = i / (1280*32); int rem = i - l*1280*32;
  int n = rem >> 5, k = rem & 31;
  wn2p[i] = (k < 24) ? wbf[O_nW2 + (size_t)l*24*1280 + (size_t)k*1280 + n] : (u16)0;
}

// ---------------- convert h0 to bf16 (into d_out scratch) ----------------
__global__ __launch_bounds__(256) void k_cvth(const void* h0, const int* __restrict__ modep,
                                              u16* __restrict__ h0b)
{
  int i = blockIdx.x * 256 + threadIdx.x;     // one per 8 elements; grid exact 6250
  if (*modep){
    ((int4*)h0b)[i] = ((const int4*)h0)[i];
  } else {
    const float* s = (const float*)h0 + (size_t)i*8;
    bf16x8 o;
    #pragma unroll
    for (int j = 0; j < 8; j++) o[j] = (short)f2b(s[j]);
    *(bf16x8*)(h0b + (size_t)i*8) = o;
  }
}

// ---------------- setup ----------------
__global__ __launch_bounds__(256) void k_setup(const void* pos0, const int* __restrict__ modep,
    float* __restrict__ deg, float* __restrict__ posf, float* __restrict__ posf0)
{
  int i = blockIdx.x * 256 + threadIdx.x;
  int mode = *modep;
  if (i < NN) deg[i] = 0.f;
  if (i < NN * 3){
    float p = mode ? b2f(((const u16*)pos0)[i]) : ((const float*)pos0)[i];
    posf[i] = p; posf0[i] = p;
  }
}

// ---------------- in-degree ----------------
__global__ __launch_bounds__(256) void k_deg(const int* __restrict__ eidx, float* __restrict__ deg)
{
  int e = blockIdx.x * 256 + threadIdx.x;
  atomicAdd(&deg[eidx[NE + e]], 1.f);
}

// ---------------- exclusive prefix sum of deg -> offs; zero cursor ----------------
__global__ __launch_bounds__(256) void k_prefix(const float* __restrict__ deg,
                                                int* __restrict__ offs, int* __restrict__ cursor)
{
  __shared__ int part[256];
  int t = threadIdx.x;
  int lo = t * 40, hi = lo + 40; if (hi > NN) hi = NN; if (lo > NN) lo = NN;
  int s = 0;
  for (int i = lo; i < hi; i++) s += (int)deg[i];
  part[t] = s;
  __syncthreads();
  for (int off = 1; off < 256; off <<= 1){
    int v = (t >= off) ? part[t - off] : 0;
    __syncthreads();
    part[t] += v;
    __syncthreads();
  }
  int run = (t == 0) ? 0 : part[t - 1];
  for (int i = lo; i < hi; i++){
    offs[i] = run;
    run += (int)deg[i];
    cursor[i] = 0;
  }
  if (t == 255) offs[NN] = run;
}

// ---------------- inverse CSR permutation: iperm[e] = slot ----------------
__global__ __launch_bounds__(256) void k_scatter(const int* __restrict__ eidx,
    const int* __restrict__ offs, int* __restrict__ cursor, int* __restrict__ iperm)
{
  int e = blockIdx.x * 256 + threadIdx.x;
  int cg = eidx[NE + e];
  int p = atomicAdd(&cursor[cg], 1);
  iperm[e] = offs[cg] + p;
}

// ---------------- initial GEMM: BK=64, XOR-swizzled LDS, XCD-grouped mapping ----------------
__global__ __launch_bounds__(256) void k_gemm_init(const u16* __restrict__ h0b,
    const u16* __restrict__ wembT, const u16* __restrict__ wbf, u16* __restrict__ Cb)
{
  __shared__ u16 As[128*64];   // 16 KB, [row][kchunk^(row&7)]
  __shared__ u16 Bs[128*64];
  int bid = blockIdx.x;                       // grid 800
  int bm = (bid & 7) + 8 * (bid / 80);
  int bn = (bid >> 3) % 10;
  if (bm >= 79) return;
  int t = threadIdx.x;
  int lane = t & 63, wv = t >> 6;
  int m0 = bm * 128, n0 = bn * 128;
  int col = lane & 15, quad = lane >> 4;
  int wm = wv & 1, wn = wv >> 1;
  f32x4 acc[4][4];
  #pragma unroll
  for (int mi = 0; mi < 4; mi++)
    #pragma unroll
    for (int ni = 0; ni < 4; ni++) acc[mi][ni] = (f32x4){0.f,0.f,0.f,0.f};

  for (int k0 = 0; k0 < DD; k0 += 64){
    #pragma unroll
    for (int is = 0; is < 4; is++){
      int flat = is*256 + t;                 // 1024 chunks of 16B
      int row = flat >> 3, kcp = flat & 7;
      int src = (kcp ^ (row & 7)) * 8;
      int grow = m0 + row; if (grow > NN-1) grow = NN-1;
      gll16(h0b + (size_t)grow*DD + k0 + src, As + flat*8);
    }
    #pragma unroll
    for (int is = 0; is < 4; is++){
      int flat = is*256 + t;
      int row = flat >> 3, kcp = flat & 7;
      int src = (kcp ^ (row & 7)) * 8;
      gll16(wembT + (size_t)(n0 + row)*DD + k0 + src, Bs + flat*8);
    }
    __builtin_amdgcn_s_waitcnt(0x0f70);   // vmcnt(0)
    __syncthreads();
    #pragma unroll
    for (int ks = 0; ks < 2; ks++){
      bf16x8 af[4], bfv[4];
      #pragma unroll
      for (int mi = 0; mi < 4; mi++){
        int row = wm*64 + mi*16 + col;
        int ch = (ks*4 + quad) ^ (row & 7);
        af[mi] = *(const bf16x8*)&As[row*64 + ch*8];
      }
      #pragma unroll
      for (int ni = 0; ni < 4; ni++){
        int row = wn*64 + ni*16 + col;
        int ch = (ks*4 + quad) ^ (row & 7);
        bfv[ni] = *(const bf16x8*)&Bs[row*64 + ch*8];
      }
      #pragma unroll
      for (int mi = 0; mi < 4; mi++)
        #pragma unroll
        for (int ni = 0; ni < 4; ni++)
          acc[mi][ni] = __builtin_amdgcn_mfma_f32_16x16x32_bf16(af[mi], bfv[ni], acc[mi][ni], 0, 0, 0);
    }
    __syncthreads();
  }
  #pragma unroll
  for (int ni = 0; ni < 4; ni++){
    int cc = n0 + wn*64 + ni*16 + col;
    float bias = b2f(wbf[O_nembB + cc]);
    #pragma unroll
    for (int mi = 0; mi < 4; mi++){
      #pragma unroll
      for (int rr = 0; rr < 4; rr++){
        int row = m0 + wm*64 + mi*16 + quad*4 + rr;
        if (row < NN) Cb[(size_t)row*DD + cc] = f2b(acc[mi][ni][rr] + bias);
      }
    }
  }
}

// ---------------- per-layer proj: direct-stream, K split across 4 waves, no K-loop barriers ----
__global__ __launch_bounds__(256) void k_gemm_proj(const u16* __restrict__ hbm,
    const u16* __restrict__ wproj, int layer,
    float* __restrict__ Ab, float* __restrict__ Bb, float* __restrict__ Mb)
{
  __shared__ float paccS[80*16];
  int t = threadIdx.x;
  int lane = t & 63, wv = t >> 6;
  int m0 = blockIdx.x * 16;                 // 625 blocks, NN = 625*16 exact
  int col = lane & 15, quad = lane >> 4;
  for (int i = t; i < 1280; i += 256) paccS[i] = 0.f;
  __syncthreads();
  const u16* wp = wproj + (size_t)layer * 80 * 1280;
  f32x4 acc5[5];
  #pragma unroll
  for (int ni = 0; ni < 5; ni++) acc5[ni] = (f32x4){0.f,0.f,0.f,0.f};
  #pragma unroll
  for (int kk = 0; kk < 10; kk++){
    int kb = wv*320 + kk*32;
    bf16x8 a = *(const bf16x8*)&hbm[(size_t)(m0 + col)*DD + kb + quad*8];
    #pragma unroll
    for (int ni = 0; ni < 5; ni++){
      bf16x8 b = *(const bf16x8*)&wp[(size_t)(ni*16 + col)*DD + kb + quad*8];
      acc5[ni] = __builtin_amdgcn_mfma_f32_16x16x32_bf16(a, b, acc5[ni], 0, 0, 0);
    }
  }
  #pragma unroll
  for (int ni = 0; ni < 5; ni++)
    #pragma unroll
    for (int rr = 0; rr < 4; rr++)
      atomicAdd(&paccS[(ni*16 + col)*16 + quad*4 + rr], acc5[ni][rr]);
  __syncthreads();
  for (int i = t; i < 1280; i += 256){
    int n = i >> 4, m = i & 15;
    if (n < 72){
      int rg = (n >= 48) ? 2 : (n >= 24 ? 1 : 0);
      int cc = n - rg*24;
      float* base = (rg == 0) ? Ab : (rg == 1) ? Bb : Mb;
      base[(m0 + m)*24 + cc] = paccS[i];
    }
  }
}

// ---------------- edge kernel: CSR-slot stores ----------------
__global__ __launch_bounds__(256) void k_edge(const int* __restrict__ eidx,
    const int* __restrict__ iperm,
    const float* __restrict__ posf, const float* __restrict__ posf0,
    const float* __restrict__ Ab, const float* __restrict__ Bb,
    const u16* __restrict__ wbf, int layer, int do_coord,
    u16* __restrict__ msgu, float* __restrict__ wcdbuf)
{
  __shared__ float sW1e[16*24], sWr[24], sB1[24], sW2[24*24], sB2[24];
  __shared__ float sCW1[24*24], sCB1[24], sCW2[24];
  int t = threadIdx.x;
  const u16* w1l = wbf + O_msgW1 + (size_t)layer * 2577 * 24;
  for (int i = t; i < 16*24; i += 256) sW1e[i] = b2f(w1l[2560*24 + i]);
  for (int i = t; i < 24; i += 256){
    sWr[i] = b2f(w1l[2576*24 + i]);
    sB1[i] = b2f(wbf[O_msgB1 + layer*24 + i]);
    sB2[i] = b2f(wbf[O_msgB2 + layer*24 + i]);
  }
  for (int i = t; i < 576; i += 256) sW2[i] = b2f(wbf[O_msgW2 + layer*576 + i]);
  if (do_coord){
    for (int i = t; i < 576; i += 256) sCW1[i] = b2f(wbf[O_cW1 + layer*576 + i]);
    for (int i = t; i < 24; i += 256){
      sCB1[i] = b2f(wbf[O_cB1 + layer*24 + i]);
      sCW2[i] = b2f(wbf[O_cW2 + layer*24 + i]);
    }
  }
  __syncthreads();
  int e = blockIdx.x * 256 + t;
  int r = eidx[e], cg = eidx[NE + e];
  int slot = iperm[e];
  float cdx = posf[r*3+0] - posf[cg*3+0];
  float cdy = posf[r*3+1] - posf[cg*3+1];
  float cdz = posf[r*3+2] - posf[cg*3+2];
  float radial = cdx*cdx + cdy*cdy + cdz*cdz;
  float ex = posf0[r*3+0] - posf0[cg*3+0];
  float ey = posf0[r*3+1] - posf0[cg*3+1];
  float ez = posf0[r*3+2] - posf0[cg*3+2];
  float dist = sqrtf(ex*ex + ey*ey + ez*ez);
  const float FR[8] = {1.f, 0.31622776601683794f, 0.1f, 0.03162277660168379f,
                       0.01f, 0.0031622776601683794f, 0.001f, 0.00031622776601683794f};
  float eav[16];
  #pragma unroll
  for (int j = 0; j < 8; j++){
    float ang = dist * FR[j];
    eav[2*j]   = __sinf(ang);
    eav[2*j+1] = __cosf(ang);
  }
  float acc[24];
  const float4* ap  = (const float4*)(Ab + cg * 24);
  const float4* bp4 = (const float4*)(Bb + r * 24);
  #pragma unroll
  for (int q = 0; q < 6; q++){
    float4 a4 = ap[q], b4 = bp4[q];
    acc[q*4+0] = a4.x + b4.x; acc[q*4+1] = a4.y + b4.y;
    acc[q*4+2] = a4.z + b4.z; acc[q*4+3] = a4.w + b4.w;
  }
  #pragma unroll
  for (int m = 0; m < 24; m++) acc[m] += sB1[m] + radial * sWr[m];
  #pragma unroll
  for (int k = 0; k < 16; k++){
    #pragma unroll
    for (int m = 0; m < 24; m++) acc[m] += eav[k] * sW1e[k*24 + m];
  }
  #pragma unroll
  for (int m = 0; m < 24; m++) acc[m] = silu_f(acc[m]);
  float msg[24];
  #pragma unroll
  for (int m = 0; m < 24; m++){
    float v = sB2[m];
    #pragma unroll
    for (int k = 0; k < 24; k++) v += acc[k] * sW2[k*24 + m];
    msg[m] = silu_f(v);
  }
  {
    bf16x8 v0, v1, v2;
    #pragma unroll
    for (int j = 0; j < 8; j++){
      v0[j] = (short)f2b(msg[j]);
      v1[j] = (short)f2b(msg[8+j]);
      v2[j] = (short)f2b(msg[16+j]);
    }
    u16* mp = msgu + (size_t)slot * 24;
    *(bf16x8*)(mp)      = v0;
    *(bf16x8*)(mp + 8)  = v1;
    *(bf16x8*)(mp + 16) = v2;
  }
  if (do_coord){
    float w = 0.f;
    #pragma unroll
    for (int m = 0; m < 24; m++){
      float v = sCB1[m];
      #pragma unroll
      for (int k = 0; k < 24; k++) v += msg[k] * sCW1[k*24 + m];
      w += silu_f(v) * sCW2[m];
    }
    wcdbuf[(size_t)slot*3+0] = cdx * w;
    wcdbuf[(size_t)slot*3+1] = cdy * w;
    wcdbuf[(size_t)slot*3+2] = cdz * w;
  }
}

// ---------------- aggregation: contiguous CSR reads ----------------
__global__ __launch_bounds__(256) void k_agg(const int* __restrict__ offs,
    const u16* __restrict__ msgu, const float* __restrict__ wcdbuf,
    float* __restrict__ magg, float* __restrict__ posf,
    int do_coord, int writeout, void* __restrict__ outp, const int* __restrict__ modep)
{
  int wv = threadIdx.x >> 6, lane = threadIdx.x & 63;
  int n = blockIdx.x * 4 + wv;
  int base = offs[n], cnt = offs[n+1] - base;
  float sum = 0.f;
  if (lane < 48){
    int m = (lane < 24) ? lane : lane - 24;
    for (int j = (lane < 24 ? 0 : 1); j < cnt; j += 2)
      sum += b2f(msgu[(size_t)(base+j)*24 + m]);
  }
  sum += __shfl_down(sum, 24, 64);
  if (lane < 24) magg[n*24 + lane] = sum;
  if (do_coord){
    float sc = 0.f;
    if (lane < 48){
      int c = lane % 3, jj = lane / 3;
      for (int j = jj; j < cnt; j += 16)
        sc += wcdbuf[(size_t)(base+j)*3 + c];
    }
    sc += __shfl_down(sc, 24, 64);
    sc += __shfl_down(sc, 12, 64);
    sc += __shfl_down(sc, 6, 64);
    sc += __shfl_down(sc, 3, 64);
    if (lane < 3){
      float p = posf[n*3 + lane] + sc;
      posf[n*3 + lane] = p;
      if (writeout){
        if (*modep) ((u16*)outp)[(size_t)NN*DD + n*3 + lane] = f2b(p);
        else        ((float*)outp)[(size_t)NN*DD + n*3 + lane] = p;
      }
    }
  }
}

// ---------------- combine: one wave per row, VALU h_up, shfl LN, no big LDS ----------------
__global__ __launch_bounds__(256) void k_combine(
    const float* __restrict__ Mb, const float* __restrict__ magg, const float* __restrict__ deg,
    const u16* __restrict__ wbf, const u16* __restrict__ wn2p, const int* __restrict__ modep,
    int layer, int last,
    u16* __restrict__ hbm, void* __restrict__ outp)
{
  __shared__ float smid[4][24];
  int t = threadIdx.x, wv = t >> 6, lane = t & 63;
  int r = blockIdx.x * 4 + wv;          // grid 2500, NN = 2500*4 exact
  // mid[24] for this row (lanes 0..23)
  if (lane < 24){
    const u16* w1b = wbf + O_nW1 + (size_t)layer*1304*24 + 1280*24;
    float inv = 1.f / fmaxf(deg[r], 1.f);
    float a = Mb[r*24 + lane] + b2f(wbf[O_nB1 + layer*24 + lane]);
    #pragma unroll
    for (int j = 0; j < 24; j++)
      a += magg[r*24 + j] * inv * b2f(w1b[j*24 + lane]);
    smid[wv][lane] = silu_f(a);
  }
  __syncthreads();
  float mid[24];
  #pragma unroll
  for (int q = 0; q < 6; q++){
    float4 m4 = *(const float4*)&smid[wv][q*4];
    mid[q*4]=m4.x; mid[q*4+1]=m4.y; mid[q*4+2]=m4.z; mid[q*4+3]=m4.w;
  }
  int c0 = lane * 20;
  // residual (coalesced uint2 loads) + b2
  float acc[20];
  {
    const uint2* rp = (const uint2*)(hbm + (size_t)r*1280 + c0);
    const uint2* bp2 = (const uint2*)(wbf + O_nB2 + (size_t)layer*1280 + c0);
    #pragma unroll
    for (int q = 0; q < 5; q++){
      uint2 v = rp[q], b = bp2[q];
      acc[q*4+0] = b2f((u16)(v.x & 0xffff)) + b2f((u16)(b.x & 0xffff));
      acc[q*4+1] = b2f((u16)(v.x >> 16))    + b2f((u16)(b.x >> 16));
      acc[q*4+2] = b2f((u16)(v.y & 0xffff)) + b2f((u16)(b.y & 0xffff));
      acc[q*4+3] = b2f((u16)(v.y >> 16))    + b2f((u16)(b.y >> 16));
    }
  }
  // h_up: per col, 24-FMA dot against K-padded wn2p rows (L2-hot)
  const u16* wp = wn2p + ((size_t)layer*1280 + c0)*32;
  #pragma unroll
  for (int i = 0; i < 20; i++){
    const bf16x8* wrow = (const bf16x8*)(wp + (size_t)i*32);
    bf16x8 w0 = wrow[0], w1 = wrow[1], w2v = wrow[2];
    float s = 0.f;
    #pragma unroll
    for (int k = 0; k < 8; k++) s += mid[k]    * b2f((u16)w0[k]);
    #pragma unroll
    for (int k = 0; k < 8; k++) s += mid[8+k]  * b2f((u16)w1[k]);
    #pragma unroll
    for (int k = 0; k < 8; k++) s += mid[16+k] * b2f((u16)w2v[k]);
    acc[i] += s;
  }
  // LayerNorm: full row lives in this wave
  float s1 = 0.f, s2 = 0.f;
  #pragma unroll
  for (int i = 0; i < 20; i++){ s1 += acc[i]; s2 += acc[i]*acc[i]; }
  #pragma unroll
  for (int off = 1; off < 64; off <<= 1){
    s1 += __shfl_xor(s1, off, 64);
    s2 += __shfl_xor(s2, off, 64);
  }
  float mu = s1 * (1.f/1280.f);
  float rstd = rsqrtf(s2*(1.f/1280.f) - mu*mu + 1e-5f);
  u16 yb[20];
  {
    const uint2* gp2 = (const uint2*)(wbf + O_lnG + (size_t)layer*1280 + c0);
    const uint2* bp2 = (const uint2*)(wbf + O_lnB + (size_t)layer*1280 + c0);
    #pragma unroll
    for (int q = 0; q < 5; q++){
      uint2 g = gp2[q], b = bp2[q];
      float gv[4] = { b2f((u16)(g.x & 0xffff)), b2f((u16)(g.x >> 16)),
                      b2f((u16)(g.y & 0xffff)), b2f((u16)(g.y >> 16)) };
      float bv[4] = { b2f((u16)(b.x & 0xffff)), b2f((u16)(b.x >> 16)),
                      b2f((u16)(b.y & 0xffff)), b2f((u16)(b.y >> 16)) };
      #pragma unroll
      for (int j = 0; j < 4; j++)
        yb[q*4+j] = f2b((acc[q*4+j] - mu) * rstd * gv[j] + bv[j]);
    }
  }
  uint2* op = (uint2*)(hbm + (size_t)r*1280 + c0);
  #pragma unroll
  for (int q = 0; q < 5; q++){
    uint2 v;
    v.x = (unsigned)yb[q*4]   | ((unsigned)yb[q*4+1] << 16);
    v.y = (unsigned)yb[q*4+2] | ((unsigned)yb[q*4+3] << 16);
    op[q] = v;
  }
  if (last){
    if (*modep){
      uint2* o2 = (uint2*)((u16*)outp + (size_t)r*1280 + c0);
      #pragma unroll
      for (int q = 0; q < 5; q++){
        uint2 v;
        v.x = (unsigned)yb[q*4]   | ((unsigned)yb[q*4+1] << 16);
        v.y = (unsigned)yb[q*4+2] | ((unsigned)yb[q*4+3] << 16);
        o2[q] = v;
      }
    } else {
      float* of = (float*)outp + (size_t)r*1280 + c0;
      #pragma unroll
      for (int i = 0; i < 20; i++) of[i] = b2f(yb[i]);
    }
  }
}

extern "C" void kernel_launch(void* const* d_in, const int* in_sizes, int n_in,
                              void* d_out, int out_size, void* d_ws, size_t ws_size,
                              hipStream_t stream)
{
  const void* h0    = d_in[0];
  const void* pos0  = d_in[1];
  const int*  eidx  = (const int*)d_in[2];

  char* w = (char*)d_ws;
  auto take = [&](size_t bytes)->char*{
    char* p = w; w += (bytes + 255) & ~(size_t)255; return p;
  };
  int*   modep  = (int*)  take(256);
  u16*   wbf    = (u16*)  take((size_t)TOTW * 2);
  u16*   wembT  = (u16*)  take((size_t)DD * DD * 2);
  u16*   wproj  = (u16*)  take((size_t)6 * 80 * 1280 * 2);
  u16*   wn2p   = (u16*)  take((size_t)6 * 1280 * 32 * 2);
  u16*   hbm    = (u16*)  take((size_t)NN * DD * 2);
  float* Ab     = (float*)take((size_t)NN * MM * 4);
  float* Bb     = (float*)take((size_t)NN * MM * 4);
  float* Mb     = (float*)take((size_t)NN * MM * 4);
  float* magg   = (float*)take((size_t)NN * MM * 4);
  float* deg    = (float*)take((size_t)NN * 4);
  float* posf   = (float*)take((size_t)NN * 3 * 4);
  float* posf0  = (float*)take((size_t)NN * 3 * 4);
  int*   offs   = (int*)  take((size_t)(NN + 1) * 4);
  int*   cursor = (int*)  take((size_t)NN * 4);
  int*   iperm  = (int*)  take((size_t)NE * 4);

  // d_out as scratch: h0b until gemm_init; msg/wcd inside the layer loop.
  u16*   h0b    = (u16*)d_out;
  u16*   msgu   = (u16*)d_out;                                    // 7.68 MB
  float* wcdbuf = (float*)((char*)d_out + (size_t)NE * 24 * 2);   // +1.92 MB

  k_sniff<<<1, 256, 0, stream>>>((const u16*)h0, modep);
  k_cvtw<<<(TOTW + 255)/256, 256, 0, stream>>>(modep,
      d_in[3], d_in[4], d_in[5], d_in[6], d_in[7], d_in[8], d_in[9], d_in[10],
      d_in[11], d_in[12], d_in[13], d_in[14], d_in[15], d_in[16], d_in[17], wbf);
  k_tr<<<1600, 256, 0, stream>>>(wbf + O_nembW, wembT);
  k_packproj<<<(6*80*1280 + 255)/256, 256, 0, stream>>>(wbf, wproj);
  k_packw2<<<6*1280*32/256, 256, 0, stream>>>(wbf, wn2p);
  k_cvth<<<NN*DD/8/256, 256, 0, stream>>>(h0, modep, h0b);
  k_setup<<<(NN*3 + 255)/256, 256, 0, stream>>>(pos0, modep, deg, posf, posf0);
  k_deg<<<NE/256, 256, 0, stream>>>(eidx, deg);
  k_prefix<<<1, 256, 0, stream>>>(deg, offs, cursor);
  k_scatter<<<NE/256, 256, 0, stream>>>(eidx, offs, cursor, iperm);
  k_gemm_init<<<800, 256, 0, stream>>>(h0b, wembT, wbf, hbm);
  for (int l = 0; l < 6; l++){
    int dc = (l < 5) ? 1 : 0;
    k_gemm_proj<<<625, 256, 0, stream>>>(hbm, wproj, l, Ab, Bb, Mb);
    k_edge<<<NE/256, 256, 0, stream>>>(eidx, iperm, posf, posf0, Ab, Bb, wbf, l, dc, msgu, wcdbuf);
    k_agg<<<2500, 256, 0, stream>>>(offs, msgu, wcdbuf, magg, posf,
                                    dc, (l == 4) ? 1 : 0, d_out, modep);
    k_combine<<<2500, 256, 0, stream>>>(Mb, magg, deg, wbf, wn2p, modep,
                                        l, (l == 5) ? 1 : 0, hbm, d_out);
  }
}

// Round 9
// 847.805 us; speedup vs baseline: 1.5233x; 1.5233x over previous
//
#include <hip/hip_runtime.h>

#define NN 10000
#define NE 160000
#define DD 1280
#define MM 24

typedef __attribute__((ext_vector_type(8))) short bf16x8;
typedef __attribute__((ext_vector_type(4))) float f32x4;
typedef unsigned short u16;

// canonical bf16 weight-workspace offsets (elements)
#define O_nembW 0
#define O_nembB 1638400
#define O_msgW1 1639680
#define O_msgB1 2010880
#define O_msgW2 2011136
#define O_msgB2 2014592
#define O_cW1   2014848
#define O_cB1   2017792
#define O_cW2   2017920
#define O_nW1   2018048
#define O_nB1   2205824
#define O_nW2   2206080
#define O_nB2   2390400
#define O_lnG   2398080
#define O_lnB   2405760
#define TOTW    2413440

__device__ __forceinline__ float b2f(u16 u){
  union { unsigned int i; float f; } v; v.i = ((unsigned int)u) << 16; return v.f;
}
__device__ __forceinline__ u16 f2b(float f){
  union { float f; unsigned int i; } v; v.f = f;
  return (u16)((v.i + 0x7fffu + ((v.i >> 16) & 1u)) >> 16);
}
__device__ __forceinline__ float silu_f(float x){ return x / (1.f + __expf(-x)); }

__device__ __forceinline__ void gll16(const u16* g, u16* l){
  __builtin_amdgcn_global_load_lds(
      (const __attribute__((address_space(1))) void*)g,
      (__attribute__((address_space(3))) void*)l, 16, 0, 0);
}

// ---------------- dtype sniffer ----------------
__global__ __launch_bounds__(256) void k_sniff(const u16* __restrict__ h0, int* __restrict__ modep)
{
  __shared__ int cnt;
  if (threadIdx.x == 0) cnt = 0;
  __syncthreads();
  int local = 0;
  for (int i = threadIdx.x; i < 16384; i += 256){
    unsigned int e = (h0[i] >> 7) & 0xFF;
    if (e >= 0xE0) local++;
  }
  atomicAdd(&cnt, local);
  __syncthreads();
  if (threadIdx.x == 0) *modep = (cnt > 16) ? 0 : 1;   // 0=fp32 inputs, 1=bf16 inputs
}

// ---------------- convert all weights to canonical bf16 ----------------
__global__ __launch_bounds__(256) void k_cvtw(const int* __restrict__ modep,
    const void* p0, const void* p1, const void* p2, const void* p3, const void* p4,
    const void* p5, const void* p6, const void* p7, const void* p8, const void* p9,
    const void* p10, const void* p11, const void* p12, const void* p13, const void* p14,
    u16* __restrict__ wbf)
{
  int i = blockIdx.x * 256 + threadIdx.x;
  if (i >= TOTW) return;
  int mode = *modep;
  const void* src; int j; int sz;
  if      (i < O_nembB){ src = p0;  j = i - O_nembW; sz = 1638400; }
  else if (i < O_msgW1){ src = p1;  j = i - O_nembB; sz = 1280; }
  else if (i < O_msgB1){ src = p2;  j = i - O_msgW1; sz = 371088; }
  else if (i < O_msgW2){ src = p3;  j = i - O_msgB1; sz = 144; }
  else if (i < O_msgB2){ src = p4;  j = i - O_msgW2; sz = 3456; }
  else if (i < O_cW1)  { src = p5;  j = i - O_msgB2; sz = 144; }
  else if (i < O_cB1)  { src = p6;  j = i - O_cW1;   sz = 2880; }
  else if (i < O_cW2)  { src = p7;  j = i - O_cB1;   sz = 120; }
  else if (i < O_nW1)  { src = p8;  j = i - O_cW2;   sz = 120; }
  else if (i < O_nB1)  { src = p9;  j = i - O_nW1;   sz = 187776; }
  else if (i < O_nW2)  { src = p10; j = i - O_nB1;   sz = 144; }
  else if (i < O_nB2)  { src = p11; j = i - O_nW2;   sz = 184320; }
  else if (i < O_lnG)  { src = p12; j = i - O_nB2;   sz = 7680; }
  else if (i < O_lnB)  { src = p13; j = i - O_lnG;   sz = 7680; }
  else                 { src = p14; j = i - O_lnB;   sz = 7680; }
  u16 v = 0;
  if (j < sz) v = mode ? ((const u16*)src)[j] : f2b(((const float*)src)[j]);
  wbf[i] = v;
}

// ---------------- tiled transpose of node_emb_W: Wt[n][k] = W[k][n] ----------------
__global__ __launch_bounds__(256) void k_tr(const u16* __restrict__ win, u16* __restrict__ wout)
{
  __shared__ u16 tile[32][33];
  int bx = blockIdx.x % 40, by = blockIdx.x / 40;
  int tc = threadIdx.x & 31, tr = threadIdx.x >> 5;
  #pragma unroll
  for (int p = 0; p < 4; p++){
    int r = p*8 + tr;
    tile[r][tc] = win[(size_t)(by*32 + r)*1280 + bx*32 + tc];
  }
  __syncthreads();
  #pragma unroll
  for (int p = 0; p < 4; p++){
    int r = p*8 + tr;
    wout[(size_t)(bx*32 + r)*1280 + by*32 + tc] = tile[tc][r];
  }
}

// ---------------- pack per-layer proj weights transposed: wproj[l][n(80)][k(1280)] ----------
__global__ __launch_bounds__(256) void k_packproj(const u16* __restrict__ wbf, u16* __restrict__ wproj)
{
  int i = blockIdx.x * 256 + threadIdx.x;
  if (i >= 6*80*1280) return;
  int l = i / (80*1280);
  int rem = i - l*80*1280;
  int n = rem / 1280;
  int k = rem - n*1280;
  u16 v = 0;
  if (n < 24)       v = wbf[O_msgW1 + (size_t)l*2577*24 + (size_t)k*24 + n];
  else if (n < 48)  v = wbf[O_msgW1 + (size_t)l*2577*24 + (size_t)(1280+k)*24 + (n-24)];
  else if (n < 72)  v = wbf[O_nW1   + (size_t)l*1304*24 + (size_t)k*24 + (n-48)];
  wproj[i] = v;
}

// ---------------- pack nW2 transposed + K-padded: wn2p[l][n(1280)][k(32)] ----------------
__global__ __launch_bounds__(256) void k_packw2(const u16* __restrict__ wbf, u16* __restrict__ wn2p)
{
  int i = blockIdx.x * 256 + threadIdx.x;    // 6*1280*32 = 245760, grid exact
  int l = i / (1280*32); int rem = i - l*1280*32;
  int n = rem >> 5, k = rem & 31;
  wn2p[i] = (k < 24) ? wbf[O_nW2 + (size_t)l*24*1280 + (size_t)k*1280 + n] : (u16)0;
}

// ---------------- convert h0 to bf16 (into d_out scratch) ----------------
__global__ __launch_bounds__(256) void k_cvth(const void* h0, const int* __restrict__ modep,
                                              u16* __restrict__ h0b)
{
  int i = blockIdx.x * 256 + threadIdx.x;     // one per 8 elements; grid exact 6250
  if (*modep){
    ((int4*)h0b)[i] = ((const int4*)h0)[i];
  } else {
    const float* s = (const float*)h0 + (size_t)i*8;
    bf16x8 o;
    #pragma unroll
    for (int j = 0; j < 8; j++) o[j] = (short)f2b(s[j]);
    *(bf16x8*)(h0b + (size_t)i*8) = o;
  }
}

// ---------------- setup ----------------
__global__ __launch_bounds__(256) void k_setup(const void* pos0, const int* __restrict__ modep,
    float* __restrict__ deg, float* __restrict__ posf, float* __restrict__ posf0)
{
  int i = blockIdx.x * 256 + threadIdx.x;
  int mode = *modep;
  if (i < NN) deg[i] = 0.f;
  if (i < NN * 3){
    float p = mode ? b2f(((const u16*)pos0)[i]) : ((const float*)pos0)[i];
    posf[i] = p; posf0[i] = p;
  }
}

// ---------------- in-degree ----------------
__global__ __launch_bounds__(256) void k_deg(const int* __restrict__ eidx, float* __restrict__ deg)
{
  int e = blockIdx.x * 256 + threadIdx.x;
  atomicAdd(&deg[eidx[NE + e]], 1.f);
}

// ---------------- exclusive prefix sum of deg -> offs; zero cursor ----------------
__global__ __launch_bounds__(256) void k_prefix(const float* __restrict__ deg,
                                                int* __restrict__ offs, int* __restrict__ cursor)
{
  __shared__ int part[256];
  int t = threadIdx.x;
  int lo = t * 40, hi = lo + 40; if (hi > NN) hi = NN; if (lo > NN) lo = NN;
  int s = 0;
  for (int i = lo; i < hi; i++) s += (int)deg[i];
  part[t] = s;
  __syncthreads();
  for (int off = 1; off < 256; off <<= 1){
    int v = (t >= off) ? part[t - off] : 0;
    __syncthreads();
    part[t] += v;
    __syncthreads();
  }
  int run = (t == 0) ? 0 : part[t - 1];
  for (int i = lo; i < hi; i++){
    offs[i] = run;
    run += (int)deg[i];
    cursor[i] = 0;
  }
  if (t == 255) offs[NN] = run;
}

// ---------------- scatter edges into CSR order ----------------
__global__ __launch_bounds__(256) void k_scatter(const int* __restrict__ eidx,
    const int* __restrict__ offs, int* __restrict__ cursor, int* __restrict__ perm)
{
  int e = blockIdx.x * 256 + threadIdx.x;
  int cg = eidx[NE + e];
  int p = atomicAdd(&cursor[cg], 1);
  perm[offs[cg] + p] = e;
}

// ---------------- initial GEMM: 64x128 tiles, XCD-grouped, bank-swizzled ----------------
__global__ __launch_bounds__(256) void k_gemm_init(const u16* __restrict__ h0b,
    const u16* __restrict__ wembT, const u16* __restrict__ wbf, u16* __restrict__ Cb)
{
  __shared__ u16 As[64*32];    // 4 KB, chunk c of row r stored at c^((r>>1)&3)
  __shared__ u16 Bs[128*32];   // 8 KB
  int bid = blockIdx.x;                       // grid 1600
  int bm = (bid & 7) + 8 * (bid / 80);        // XCD = bid%8: one bm's 10 bn-tiles per XCD
  int bn = (bid >> 3) % 10;
  if (bm >= 157) return;
  int t = threadIdx.x;
  int lane = t & 63, wv = t >> 6;
  int m0 = bm * 64, n0 = bn * 128;
  int col = lane & 15, quad = lane >> 4;
  f32x4 acc[4][2];
  #pragma unroll
  for (int mi = 0; mi < 4; mi++)
    #pragma unroll
    for (int ni = 0; ni < 2; ni++) acc[mi][ni] = (f32x4){0.f,0.f,0.f,0.f};

  for (int k0 = 0; k0 < DD; k0 += 32){
    { int row = t >> 2, kcp = t & 3;                  // A: 256 chunks of 16B
      int src = (kcp ^ ((row >> 1) & 3)) * 8;
      int grow = m0 + row; if (grow > NN-1) grow = NN-1;
      gll16(h0b + (size_t)grow*DD + k0 + src, As + t*8); }
    #pragma unroll
    for (int is = 0; is < 2; is++){                   // B: 512 chunks
      int flat = is*256 + t;
      int row = flat >> 2, kcp = flat & 3;
      int src = (kcp ^ ((row >> 1) & 3)) * 8;
      gll16(wembT + (size_t)(n0 + row)*DD + k0 + src, Bs + flat*8);
    }
    __builtin_amdgcn_s_waitcnt(0x0f70);   // vmcnt(0)
    __syncthreads();
    bf16x8 af[4], bfv[2];
    #pragma unroll
    for (int mi = 0; mi < 4; mi++){
      int row = mi*16 + col;
      int ch = quad ^ ((row >> 1) & 3);
      af[mi] = *(const bf16x8*)&As[row*32 + ch*8];
    }
    #pragma unroll
    for (int ni = 0; ni < 2; ni++){
      int row = wv*32 + ni*16 + col;
      int ch = quad ^ ((row >> 1) & 3);
      bfv[ni] = *(const bf16x8*)&Bs[row*32 + ch*8];
    }
    #pragma unroll
    for (int mi = 0; mi < 4; mi++)
      #pragma unroll
      for (int ni = 0; ni < 2; ni++)
        acc[mi][ni] = __builtin_amdgcn_mfma_f32_16x16x32_bf16(af[mi], bfv[ni], acc[mi][ni], 0, 0, 0);
    __syncthreads();
  }
  #pragma unroll
  for (int ni = 0; ni < 2; ni++){
    int cc = n0 + wv*32 + ni*16 + col;
    float bias = b2f(wbf[O_nembB + cc]);
    #pragma unroll
    for (int mi = 0; mi < 4; mi++){
      #pragma unroll
      for (int rr = 0; rr < 4; rr++){
        int row = m0 + mi*16 + quad*4 + rr;
        if (row < NN) Cb[(size_t)row*DD + cc] = f2b(acc[mi][ni][rr] + bias);
      }
    }
  }
}

// ---------------- per-layer projections: C(10000x80) = hbm @ wprojT ----------------
__global__ __launch_bounds__(128) void k_gemm_proj(const u16* __restrict__ hbm,
    const u16* __restrict__ wproj, int layer,
    float* __restrict__ Ab, float* __restrict__ Bb, float* __restrict__ Mb)
{
  __shared__ u16 As[32*32];
  __shared__ u16 Bs[80*32];
  int t = threadIdx.x;
  int lane = t & 63, wv = t >> 6;
  int m0 = blockIdx.x * 32;
  int col = lane & 15, quad = lane >> 4;
  const u16* wp = wproj + (size_t)layer * 80 * 1280;
  f32x4 acc[5];
  #pragma unroll
  for (int ni = 0; ni < 5; ni++) acc[ni] = (f32x4){0.f,0.f,0.f,0.f};

  for (int k0 = 0; k0 < DD; k0 += 32){
    { int row = t >> 2, seg = t & 3;
      int grow = m0 + row; if (grow > NN-1) grow = NN-1;
      gll16(hbm + (size_t)grow*DD + k0 + seg*8, As + t*8); }
    #pragma unroll
    for (int is = 0; is < 3; is++){
      int flat = is*128 + t;
      if (flat < 320){
        int row = flat >> 2, seg = flat & 3;
        gll16(wp + (size_t)row*DD + k0 + seg*8, Bs + flat*8);
      }
    }
    __builtin_amdgcn_s_waitcnt(0x0f70);
    __syncthreads();
    bf16x8 af = *(const bf16x8*)&As[(wv*16 + col)*32 + quad*8];
    #pragma unroll
    for (int ni = 0; ni < 5; ni++){
      bf16x8 bv = *(const bf16x8*)&Bs[(ni*16 + col)*32 + quad*8];
      acc[ni] = __builtin_amdgcn_mfma_f32_16x16x32_bf16(af, bv, acc[ni], 0, 0, 0);
    }
    __syncthreads();
  }
  #pragma unroll
  for (int ni = 0; ni < 5; ni++){
    int n = ni*16 + col;
    if (n < 72){
      int rg = (n >= 48) ? 2 : (n >= 24 ? 1 : 0);
      int cc = n - rg*24;
      float* base = (rg == 0) ? Ab : (rg == 1) ? Bb : Mb;
      #pragma unroll
      for (int rr = 0; rr < 4; rr++){
        int m = m0 + wv*16 + quad*4 + rr;
        if (m < NN) base[m*24 + cc] = acc[ni][rr];
      }
    }
  }
}

// ---------------- edge kernel: plain per-edge stores (msg as bf16), no atomics ----------------
__global__ __launch_bounds__(256) void k_edge(const int* __restrict__ eidx,
    const float* __restrict__ posf, const float* __restrict__ posf0,
    const float* __restrict__ Ab, const float* __restrict__ Bb,
    const u16* __restrict__ wbf, int layer, int do_coord,
    u16* __restrict__ msgu, float* __restrict__ wcdbuf)
{
  __shared__ float sW1e[16*24], sWr[24], sB1[24], sW2[24*24], sB2[24];
  __shared__ float sCW1[24*24], sCB1[24], sCW2[24];
  int t = threadIdx.x;
  const u16* w1l = wbf + O_msgW1 + (size_t)layer * 2577 * 24;
  for (int i = t; i < 16*24; i += 256) sW1e[i] = b2f(w1l[2560*24 + i]);
  for (int i = t; i < 24; i += 256){
    sWr[i] = b2f(w1l[2576*24 + i]);
    sB1[i] = b2f(wbf[O_msgB1 + layer*24 + i]);
    sB2[i] = b2f(wbf[O_msgB2 + layer*24 + i]);
  }
  for (int i = t; i < 576; i += 256) sW2[i] = b2f(wbf[O_msgW2 + layer*576 + i]);
  if (do_coord){
    for (int i = t; i < 576; i += 256) sCW1[i] = b2f(wbf[O_cW1 + layer*576 + i]);
    for (int i = t; i < 24; i += 256){
      sCB1[i] = b2f(wbf[O_cB1 + layer*24 + i]);
      sCW2[i] = b2f(wbf[O_cW2 + layer*24 + i]);
    }
  }
  __syncthreads();
  int e = blockIdx.x * 256 + t;
  int r = eidx[e], cg = eidx[NE + e];
  float cdx = posf[r*3+0] - posf[cg*3+0];
  float cdy = posf[r*3+1] - posf[cg*3+1];
  float cdz = posf[r*3+2] - posf[cg*3+2];
  float radial = cdx*cdx + cdy*cdy + cdz*cdz;
  float ex = posf0[r*3+0] - posf0[cg*3+0];
  float ey = posf0[r*3+1] - posf0[cg*3+1];
  float ez = posf0[r*3+2] - posf0[cg*3+2];
  float dist = sqrtf(ex*ex + ey*ey + ez*ez);
  const float FR[8] = {1.f, 0.31622776601683794f, 0.1f, 0.03162277660168379f,
                       0.01f, 0.0031622776601683794f, 0.001f, 0.00031622776601683794f};
  float eav[16];
  #pragma unroll
  for (int j = 0; j < 8; j++){
    float ang = dist * FR[j];
    eav[2*j]   = __sinf(ang);
    eav[2*j+1] = __cosf(ang);
  }
  float acc[24];
  const float4* ap  = (const float4*)(Ab + cg * 24);
  const float4* bp4 = (const float4*)(Bb + r * 24);
  #pragma unroll
  for (int q = 0; q < 6; q++){
    float4 a4 = ap[q], b4 = bp4[q];
    acc[q*4+0] = a4.x + b4.x; acc[q*4+1] = a4.y + b4.y;
    acc[q*4+2] = a4.z + b4.z; acc[q*4+3] = a4.w + b4.w;
  }
  #pragma unroll
  for (int m = 0; m < 24; m++) acc[m] += sB1[m] + radial * sWr[m];
  #pragma unroll
  for (int k = 0; k < 16; k++){
    #pragma unroll
    for (int m = 0; m < 24; m++) acc[m] += eav[k] * sW1e[k*24 + m];
  }
  #pragma unroll
  for (int m = 0; m < 24; m++) acc[m] = silu_f(acc[m]);
  float msg[24];
  #pragma unroll
  for (int m = 0; m < 24; m++){
    float v = sB2[m];
    #pragma unroll
    for (int k = 0; k < 24; k++) v += acc[k] * sW2[k*24 + m];
    msg[m] = silu_f(v);
  }
  {
    bf16x8 v0, v1, v2;
    #pragma unroll
    for (int j = 0; j < 8; j++){
      v0[j] = (short)f2b(msg[j]);
      v1[j] = (short)f2b(msg[8+j]);
      v2[j] = (short)f2b(msg[16+j]);
    }
    u16* mp = msgu + (size_t)e * 24;   // 48B stride -> 16B aligned
    *(bf16x8*)(mp)      = v0;
    *(bf16x8*)(mp + 8)  = v1;
    *(bf16x8*)(mp + 16) = v2;
  }
  if (do_coord){
    float w = 0.f;
    #pragma unroll
    for (int m = 0; m < 24; m++){
      float v = sCB1[m];
      #pragma unroll
      for (int k = 0; k < 24; k++) v += msg[k] * sCW1[k*24 + m];
      w += silu_f(v) * sCW2[m];
    }
    wcdbuf[(size_t)e*3+0] = cdx * w;
    wcdbuf[(size_t)e*3+1] = cdy * w;
    wcdbuf[(size_t)e*3+2] = cdz * w;
  }
}

// ---------------- aggregation: one wave per node over CSR lists ----------------
__global__ __launch_bounds__(256) void k_agg(const int* __restrict__ perm,
    const int* __restrict__ offs,
    const u16* __restrict__ msgu, const float* __restrict__ wcdbuf,
    float* __restrict__ magg, float* __restrict__ posf,
    int do_coord, int writeout, void* __restrict__ outp, const int* __restrict__ modep)
{
  int wv = threadIdx.x >> 6, lane = threadIdx.x & 63;
  int n = blockIdx.x * 4 + wv;           // grid 2500 exact -> 10000 nodes
  int base = offs[n], cnt = offs[n+1] - base;
  float sum = 0.f;
  if (lane < 48){
    int m = (lane < 24) ? lane : lane - 24;
    for (int j = (lane < 24 ? 0 : 1); j < cnt; j += 2)
      sum += b2f(msgu[(size_t)perm[base+j]*24 + m]);
  }
  sum += __shfl_down(sum, 24, 64);
  if (lane < 24) magg[n*24 + lane] = sum;
  if (do_coord){
    float sc = 0.f;
    if (lane < 48){
      int c = lane % 3, jj = lane / 3;
      for (int j = jj; j < cnt; j += 16)
        sc += wcdbuf[(size_t)perm[base+j]*3 + c];
    }
    sc += __shfl_down(sc, 24, 64);
    sc += __shfl_down(sc, 12, 64);
    sc += __shfl_down(sc, 6, 64);
    sc += __shfl_down(sc, 3, 64);
    if (lane < 3){
      float p = posf[n*3 + lane] + sc;
      posf[n*3 + lane] = p;
      if (writeout){
        if (*modep) ((u16*)outp)[(size_t)NN*DD + n*3 + lane] = f2b(p);
        else        ((float*)outp)[(size_t)NN*DD + n*3 + lane] = p;
      }
    }
  }
}

// ---------------- combine: mid MLP (VALU) + h_up GEMM (MFMA) + residual + LN, fused -------
__global__ __launch_bounds__(256) void k_combine(
    const float* __restrict__ Mb, const float* __restrict__ magg, const float* __restrict__ deg,
    const u16* __restrict__ wbf, const u16* __restrict__ wn2p, const int* __restrict__ modep,
    int layer, int last,
    u16* __restrict__ hbm, void* __restrict__ outp)
{
  __shared__ u16 shRes[16*1280];        // 40 KB residual rows
  __shared__ u16 midb[16*32];           // A-frag: 16 rows x K32 (padded)
  __shared__ float sW1b[576], sB1c[24], sMg[384], sMbs[384], sDeg[16];
  __shared__ float wpart[4][16][2];
  __shared__ float mrow[16][2];
  int t = threadIdx.x;
  int lane = t & 63, wv = t >> 6;
  int row0 = blockIdx.x * 16;
  // stage residual rows (16 x 1280 bf16) via global_load_lds
  #pragma unroll
  for (int it = 0; it < 10; it++){
    int flat = it*256 + t;              // 2560 chunks of 16B
    int r = flat / 160, off = (flat - r*160) * 8;
    gll16(hbm + (size_t)(row0 + r)*1280 + off, shRes + flat*8);
  }
  const u16* w1b = wbf + O_nW1 + (size_t)layer*1304*24 + 1280*24;
  for (int i = t; i < 576; i += 256) sW1b[i] = b2f(w1b[i]);
  if (t < 24) sB1c[t] = b2f(wbf[O_nB1 + layer*24 + t]);
  if (t < 16) sDeg[t] = 1.f / fmaxf(deg[row0 + t], 1.f);
  for (int i = t; i < 384; i += 256){ sMg[i] = magg[row0*24 + i]; sMbs[i] = Mb[row0*24 + i]; }
  midb[t] = 0; midb[256 + t] = 0;
  __builtin_amdgcn_s_waitcnt(0x0f70);   // vmcnt(0)
  __syncthreads();
  // mid = silu(Mb + (magg/deg)@W1b + b1), bf16 into LDS
  for (int o = t; o < 384; o += 256){
    int r = o / 24, m = o - r*24;
    float inv = sDeg[r];
    float a = sMbs[o] + sB1c[m];
    #pragma unroll
    for (int j = 0; j < 24; j++) a += sMg[r*24 + j] * inv * sW1b[j*24 + m];
    midb[r*32 + m] = f2b(silu_f(a));
  }
  __syncthreads();
  int col = lane & 15, quad = lane >> 4;
  bf16x8 af = *(const bf16x8*)&midb[col*32 + quad*8];
  int mode = *modep;
  float s1[4] = {0.f,0.f,0.f,0.f}, s2[4] = {0.f,0.f,0.f,0.f};
  float vals[20][4];
  const u16* wp = wn2p + (size_t)layer*1280*32;
  const u16* b2p = wbf + O_nB2 + (size_t)layer*1280;
  #pragma unroll
  for (int ti = 0; ti < 20; ti++){
    int n0 = wv*320 + ti*16;
    bf16x8 bfv = *(const bf16x8*)&wp[(size_t)(n0+col)*32 + quad*8];
    f32x4 acc = {0.f,0.f,0.f,0.f};
    acc = __builtin_amdgcn_mfma_f32_16x16x32_bf16(af, bfv, acc, 0, 0, 0);
    float b2 = b2f(b2p[n0 + col]);
    #pragma unroll
    for (int rr = 0; rr < 4; rr++){
      int r = quad*4 + rr;
      float hn = b2f(shRes[r*1280 + n0 + col]) + acc[rr] + b2;
      vals[ti][rr] = hn;
      s1[rr] += hn; s2[rr] += hn*hn;
    }
  }
  #pragma unroll
  for (int off = 1; off < 16; off <<= 1){
    #pragma unroll
    for (int rr = 0; rr < 4; rr++){
      s1[rr] += __shfl_xor(s1[rr], off, 64);
      s2[rr] += __shfl_xor(s2[rr], off, 64);
    }
  }
  if (col == 0){
    #pragma unroll
    for (int rr = 0; rr < 4; rr++){
      wpart[wv][quad*4+rr][0] = s1[rr];
      wpart[wv][quad*4+rr][1] = s2[rr];
    }
  }
  __syncthreads();
  if (t < 16){
    float S1 = wpart[0][t][0] + wpart[1][t][0] + wpart[2][t][0] + wpart[3][t][0];
    float S2 = wpart[0][t][1] + wpart[1][t][1] + wpart[2][t][1] + wpart[3][t][1];
    float mu = S1 * (1.f/1280.f);
    float var = S2 * (1.f/1280.f) - mu*mu;
    mrow[t][0] = mu;
    mrow[t][1] = rsqrtf(var + 1e-5f);
  }
  __syncthreads();
  const u16* gp = wbf + O_lnG + (size_t)layer*1280;
  const u16* bp = wbf + O_lnB + (size_t)layer*1280;
  #pragma unroll
  for (int ti = 0; ti < 20; ti++){
    int n0 = wv*320 + ti*16;
    int cc = n0 + col;
    float g  = b2f(gp[cc]);
    float bb = b2f(bp[cc]);
    #pragma unroll
    for (int rr = 0; rr < 4; rr++){
      int r = quad*4 + rr;
      float y = (vals[ti][rr] - mrow[r][0]) * mrow[r][1] * g + bb;
      hbm[(size_t)(row0 + r)*1280 + cc] = f2b(y);
      if (last){
        if (mode) ((u16*)outp)[(size_t)(row0+r)*1280 + cc] = f2b(y);
        else      ((float*)outp)[(size_t)(row0+r)*1280 + cc] = y;
      }
    }
  }
}

extern "C" void kernel_launch(void* const* d_in, const int* in_sizes, int n_in,
                              void* d_out, int out_size, void* d_ws, size_t ws_size,
                              hipStream_t stream)
{
  const void* h0    = d_in[0];
  const void* pos0  = d_in[1];
  const int*  eidx  = (const int*)d_in[2];

  char* w = (char*)d_ws;
  auto take = [&](size_t bytes)->char*{
    char* p = w; w += (bytes + 255) & ~(size_t)255; return p;
  };
  int*   modep  = (int*)  take(256);
  u16*   wbf    = (u16*)  take((size_t)TOTW * 2);
  u16*   wembT  = (u16*)  take((size_t)DD * DD * 2);
  u16*   wproj  = (u16*)  take((size_t)6 * 80 * 1280 * 2);
  u16*   wn2p   = (u16*)  take((size_t)6 * 1280 * 32 * 2);
  u16*   hbm    = (u16*)  take((size_t)NN * DD * 2);
  float* Ab     = (float*)take((size_t)NN * MM * 4);
  float* Bb     = (float*)take((size_t)NN * MM * 4);
  float* Mb     = (float*)take((size_t)NN * MM * 4);
  float* magg   = (float*)take((size_t)NN * MM * 4);
  float* deg    = (float*)take((size_t)NN * 4);
  float* posf   = (float*)take((size_t)NN * 3 * 4);
  float* posf0  = (float*)take((size_t)NN * 3 * 4);
  int*   offs   = (int*)  take((size_t)(NN + 1) * 4);
  int*   cursor = (int*)  take((size_t)NN * 4);
  int*   perm   = (int*)  take((size_t)NE * 4);

  // d_out as scratch: h0b until gemm_init; msg/wcd inside the layer loop.
  u16*   h0b    = (u16*)d_out;
  u16*   msgu   = (u16*)d_out;                                    // 7.68 MB
  float* wcdbuf = (float*)((char*)d_out + (size_t)NE * 24 * 2);   // +1.92 MB

  k_sniff<<<1, 256, 0, stream>>>((const u16*)h0, modep);
  k_cvtw<<<(TOTW + 255)/256, 256, 0, stream>>>(modep,
      d_in[3], d_in[4], d_in[5], d_in[6], d_in[7], d_in[8], d_in[9], d_in[10],
      d_in[11], d_in[12], d_in[13], d_in[14], d_in[15], d_in[16], d_in[17], wbf);
  k_tr<<<1600, 256, 0, stream>>>(wbf + O_nembW, wembT);
  k_packproj<<<(6*80*1280 + 255)/256, 256, 0, stream>>>(wbf, wproj);
  k_packw2<<<6*1280*32/256, 256, 0, stream>>>(wbf, wn2p);
  k_cvth<<<NN*DD/8/256, 256, 0, stream>>>(h0, modep, h0b);
  k_setup<<<(NN*3 + 255)/256, 256, 0, stream>>>(pos0, modep, deg, posf, posf0);
  k_deg<<<NE/256, 256, 0, stream>>>(eidx, deg);
  k_prefix<<<1, 256, 0, stream>>>(deg, offs, cursor);
  k_scatter<<<NE/256, 256, 0, stream>>>(eidx, offs, cursor, perm);
  k_gemm_init<<<1600, 256, 0, stream>>>(h0b, wembT, wbf, hbm);
  for (int l = 0; l < 6; l++){
    int dc = (l < 5) ? 1 : 0;
    k_gemm_proj<<<313, 128, 0, stream>>>(hbm, wproj, l, Ab, Bb, Mb);
    k_edge<<<NE/256, 256, 0, stream>>>(eidx, posf, posf0, Ab, Bb, wbf, l, dc, msgu, wcdbuf);
    k_agg<<<2500, 256, 0, stream>>>(perm, offs, msgu, wcdbuf, magg, posf,
                                    dc, (l == 4) ? 1 : 0, d_out, modep);
    k_combine<<<625, 256, 0, stream>>>(Mb, magg, deg, wbf, wn2p, modep, l, (l == 5) ? 1 : 0,
                                       hbm, d_out);
  }
}